// Round 1
// 842.683 us; speedup vs baseline: 2.9554x; 2.9554x over previous
//
#include <hip/hip_runtime.h>

#define B_ 2
#define S_ 2048
#define D_ 768
#define H_ 12
#define DK_ 64
#define BH_ (B_*H_)
#define NEGV (-1e9f)
#define SCALE 0.125f
#define MINIT (-1e30f)

typedef unsigned short u16;
typedef __attribute__((ext_vector_type(8))) short bf16x8;   // 8 bf16 (4 VGPRs)
typedef __attribute__((ext_vector_type(4))) float f32x4;    // MFMA accumulator

__device__ __forceinline__ float bf2f(u16 u){
  union { unsigned int i; float f; } v; v.i = ((unsigned int)u) << 16; return v.f;
}
__device__ __forceinline__ u16 f2bf(float f){
  union { float f; unsigned int i; } v; v.f = f;
  unsigned int x = v.i;
  return (u16)((x + 0x7FFFu + ((x >> 16) & 1u)) >> 16);
}
__device__ __forceinline__ void f4a(const float* p, float* a){
  float4 v = *(const float4*)p; a[0]=v.x; a[1]=v.y; a[2]=v.z; a[3]=v.w;
}

// ---------------- GEMM: C[r,c] = sum_k X[r,k]*W[c,k] + bias[c], M=4096,N=768,K=768
// XBF16: X is bf16 (ctx ws) else f32.
// OMODE: 0 = f32 plain [M,N]; 1 = bf16 head-split [bh][s][dk]; 2 = bf16 head-split V-transposed [bh][dk][s]
template<bool XBF16, int OMODE>
__device__ __forceinline__ void gemm64(const void* __restrict__ Xp_, const float* __restrict__ W,
                                       const float* __restrict__ bias, void* __restrict__ outp)
{
  const int row0 = blockIdx.x * 64;
  const int col0 = blockIdx.y * 64;
  const int tx = threadIdx.x, ty = threadIdx.y;
  const int tid = ty*16 + tx;

  __shared__ float As[16][68];
  __shared__ float Bs[16][68];

  float acc[4][4] = {};

  const int mrow = tid >> 2;        // 0..63
  const int kq   = (tid & 3) * 4;   // 0,4,8,12
  const float* wp = W + (size_t)(col0 + mrow) * D_ + kq;

  for (int k0 = 0; k0 < D_; k0 += 16) {
    __syncthreads();
    if constexpr (XBF16) {
      const u16* X = (const u16*)Xp_;
      ushort4 ua = *(const ushort4*)(X + (size_t)(row0 + mrow) * D_ + kq + k0);
      As[kq+0][mrow]=bf2f(ua.x); As[kq+1][mrow]=bf2f(ua.y); As[kq+2][mrow]=bf2f(ua.z); As[kq+3][mrow]=bf2f(ua.w);
    } else {
      const float* X = (const float*)Xp_;
      float4 fa = *(const float4*)(X + (size_t)(row0 + mrow) * D_ + kq + k0);
      As[kq+0][mrow]=fa.x; As[kq+1][mrow]=fa.y; As[kq+2][mrow]=fa.z; As[kq+3][mrow]=fa.w;
    }
    float4 fb = *(const float4*)(wp + k0);
    Bs[kq+0][mrow]=fb.x; Bs[kq+1][mrow]=fb.y; Bs[kq+2][mrow]=fb.z; Bs[kq+3][mrow]=fb.w;
    __syncthreads();
    #pragma unroll
    for (int kk=0; kk<16; kk++){
      float a[4], b[4];
      f4a(&As[kk][ty*4], a);
      f4a(&Bs[kk][tx*4], b);
      #pragma unroll
      for (int i=0;i<4;i++)
        #pragma unroll
        for (int j=0;j<4;j++)
          acc[i][j] += a[i]*b[j];
    }
  }

  float bb[4];
  #pragma unroll
  for (int j=0;j<4;j++) bb[j] = bias[col0 + tx*4 + j];

  if constexpr (OMODE==1) {
    u16* out = (u16*)outp;
    const int h = col0 >> 6;       // tile width 64 == DK -> single head per tile
    const int batch = row0 >> 11;  // tile rows never cross batch boundary
    #pragma unroll
    for (int i=0;i<4;i++){
      int r = row0 + ty*4 + i;
      int s = r & (S_-1);
      ushort4 wv;
      wv.x = f2bf(acc[i][0]+bb[0]); wv.y = f2bf(acc[i][1]+bb[1]);
      wv.z = f2bf(acc[i][2]+bb[2]); wv.w = f2bf(acc[i][3]+bb[3]);
      *(ushort4*)(out + ((size_t)(batch*H_ + h)*S_ + s)*DK_ + tx*4) = wv;
    }
  } else if constexpr (OMODE==2) {
    // V stored transposed per head: [bh][dk][s] so attention PV B-fragments read contiguously
    u16* out = (u16*)outp;
    const int h = col0 >> 6;
    const int batch = row0 >> 11;
    const int s0 = (row0 & (S_-1)) + ty*4;
    #pragma unroll
    for (int j=0;j<4;j++){
      const int dk = tx*4 + j;
      ushort4 wv;
      wv.x = f2bf(acc[0][j]+bb[j]); wv.y = f2bf(acc[1][j]+bb[j]);
      wv.z = f2bf(acc[2][j]+bb[j]); wv.w = f2bf(acc[3][j]+bb[j]);
      *(ushort4*)(out + ((size_t)(batch*H_ + h)*DK_ + dk)*S_ + s0) = wv;
    }
  } else {
    float* out = (float*)outp;
    #pragma unroll
    for (int i=0;i<4;i++){
      int r = row0 + ty*4 + i;
      *(float4*)(out + (size_t)r*D_ + col0 + tx*4) =
          make_float4(acc[i][0]+bb[0], acc[i][1]+bb[1], acc[i][2]+bb[2], acc[i][3]+bb[3]);
    }
  }
}

__global__ __launch_bounds__(256) void proj_qkv(
    const float* __restrict__ Xq, const float* __restrict__ Xk, const float* __restrict__ Xv,
    const float* __restrict__ Wq, const float* __restrict__ bq,
    const float* __restrict__ Wk, const float* __restrict__ bk,
    const float* __restrict__ Wv, const float* __restrict__ bv,
    u16* __restrict__ qkv)
{
  const int z = blockIdx.z;
  const float* X = (z==0)?Xq:(z==1)?Xk:Xv;
  const float* W = (z==0)?Wq:(z==1)?Wk:Wv;
  const float* bia = (z==0)?bq:(z==1)?bk:bv;
  u16* out = qkv + (size_t)z * ((size_t)BH_*S_*DK_);
  if (z==2) gemm64<false, 2>((const void*)X, W, bia, (void*)out);
  else      gemm64<false, 1>((const void*)X, W, bia, (void*)out);
}

__global__ __launch_bounds__(256) void proj_o(
    const u16* __restrict__ Xc, const float* __restrict__ Wo, const float* __restrict__ bo,
    float* __restrict__ out)
{
  gemm64<true, 0>((const void*)Xc, Wo, bo, (void*)out);
}

// ---------------- attention (MFMA) ----------------
// Stage a 64x64 bf16 tile (row-major source, stride sstride) into LDS [64][72].
// 512 16B-chunks over 256 threads; writes are conflict-free (uniform 8/bank).
__device__ __forceinline__ void stage64(u16 (*dst)[72], const u16* __restrict__ src,
                                        size_t sstride, int tid)
{
  #pragma unroll
  for (int i=0;i<2;i++){
    const int cidx = tid + i*256;         // 0..511
    const int row = cidx >> 3;
    const int cc  = (cidx & 7) << 3;      // 0,8,..,56
    uint4 v = *(const uint4*)(src + (size_t)row*sstride + cc);
    *(uint4*)&dst[row][cc] = v;
  }
}

// Per block: 64 Q-rows, 4 waves, each wave owns a 16-row strip.
// MFMA 16x16x32 bf16: A m=lane&15, k=(lane>>4)*8+j (contiguous); B n=lane&15, k likewise;
// C/D col=lane&15, row=(lane>>4)*4+reg  [learn_hip m89/m92/m97-verified layouts]
__global__ __launch_bounds__(256,3) void attn(const u16* __restrict__ qkv, const int* __restrict__ mask,
                                              float* __restrict__ la, u16* __restrict__ ctx)
{
  const int bh = blockIdx.y;
  const int q0 = blockIdx.x * 64;
  const int b = bh / H_;
  const int h = bh - b*H_;
  const u16* Qp = qkv + (size_t)bh * S_ * DK_;             // [S][DK]
  const u16* Kp = qkv + (size_t)(BH_ + bh) * S_ * DK_;     // [S][DK]
  const u16* Vt = qkv + (size_t)(2*BH_ + bh) * S_ * DK_;   // [DK][S]  (transposed by proj)
  const int* Mp = mask + (size_t)b * S_ * S_;

  const int tid  = threadIdx.x;
  const int w    = tid >> 6;      // wave 0..3
  const int lane = tid & 63;
  const int g    = lane >> 4;     // 16-lane group 0..3
  const int c    = lane & 15;

  __shared__ u16 Ks[64][72];
  __shared__ u16 Vs[64][72];      // Vs[d][k] = V[j0+k][d]
  __shared__ u16 Ps[4][16][72];   // per-wave P strip (C-layout write -> A-frag read)

  // ---- Q tile -> LDS -> A-fragments in registers ----
  stage64(Ks, Qp + (size_t)q0*DK_, DK_, tid);
  __syncthreads();
  const bf16x8 qf0 = *(const bf16x8*)&Ks[w*16 + c][g*8];
  const bf16x8 qf1 = *(const bf16x8*)&Ks[w*16 + c][g*8 + 32];

  float mt[4], lt[4];
  #pragma unroll
  for (int r=0;r<4;r++){ mt[r] = MINIT; lt[r] = 0.f; }

  // ---- pass A: per-lane online stats over this lane's 4 columns/tile ----
  for (int j0=0; j0<S_; j0+=64){
    __syncthreads();
    stage64(Ks, Kp + (size_t)j0*DK_, DK_, tid);
    __syncthreads();
    f32x4 sc[4];
    #pragma unroll
    for (int nt=0; nt<4; nt++){
      const bf16x8 kf0 = *(const bf16x8*)&Ks[nt*16 + c][g*8];
      const bf16x8 kf1 = *(const bf16x8*)&Ks[nt*16 + c][g*8 + 32];
      f32x4 z = {0.f,0.f,0.f,0.f};
      z      = __builtin_amdgcn_mfma_f32_16x16x32_bf16(qf0, kf0, z, 0,0,0);
      sc[nt] = __builtin_amdgcn_mfma_f32_16x16x32_bf16(qf1, kf1, z, 0,0,0);
    }
    #pragma unroll
    for (int r=0;r<4;r++){
      const int qi = q0 + w*16 + g*4 + r;
      const int* mp = Mp + (size_t)qi*S_ + j0 + c;
      float sv[4];
      #pragma unroll
      for (int nt=0;nt<4;nt++)
        sv[nt] = mp[nt*16] ? sc[nt][r]*SCALE : NEGV;
      const float cm = fmaxf(fmaxf(sv[0],sv[1]), fmaxf(sv[2],sv[3]));
      const float mn = fmaxf(mt[r], cm);
      lt[r] = lt[r]*__expf(mt[r]-mn)
            + __expf(sv[0]-mn) + __expf(sv[1]-mn) + __expf(sv[2]-mn) + __expf(sv[3]-mn);
      mt[r] = mn;
    }
  }

  // ---- merge (m,l) across the 16 lanes of each group (butterfly, bit-identical per group) ----
  float ml[4];
  #pragma unroll
  for (int r=0;r<4;r++){
    float m = mt[r], l = lt[r];
    #pragma unroll
    for (int st=1; st<16; st<<=1){
      const float m2 = __shfl_xor(m, st);
      const float l2 = __shfl_xor(l, st);
      const float mn = fmaxf(m, m2);
      l = l*__expf(m-mn) + l2*__expf(m2-mn);
      m = mn;
    }
    ml[r] = m + __logf(fmaxf(l, 1e-30f));
  }

  // ---- pass B: recompute scores, emit log_attn, MFMA P.V ----
  f32x4 o[4];
  #pragma unroll
  for (int nt=0;nt<4;nt++) o[nt] = (f32x4){0.f,0.f,0.f,0.f};

  for (int j0=0; j0<S_; j0+=64){
    __syncthreads();
    stage64(Ks, Kp + (size_t)j0*DK_, DK_, tid);
    stage64(Vs, Vt + j0, S_, tid);
    __syncthreads();
    f32x4 sc[4];
    #pragma unroll
    for (int nt=0; nt<4; nt++){
      const bf16x8 kf0 = *(const bf16x8*)&Ks[nt*16 + c][g*8];
      const bf16x8 kf1 = *(const bf16x8*)&Ks[nt*16 + c][g*8 + 32];
      f32x4 z = {0.f,0.f,0.f,0.f};
      z      = __builtin_amdgcn_mfma_f32_16x16x32_bf16(qf0, kf0, z, 0,0,0);
      sc[nt] = __builtin_amdgcn_mfma_f32_16x16x32_bf16(qf1, kf1, z, 0,0,0);
    }
    float lvv[4][4];
    #pragma unroll
    for (int r=0;r<4;r++){
      const int qi = q0 + w*16 + g*4 + r;
      const int* mp = Mp + (size_t)qi*S_ + j0 + c;
      #pragma unroll
      for (int nt=0;nt<4;nt++){
        const float s  = mp[nt*16] ? sc[nt][r]*SCALE : NEGV;
        const float lv = fminf(s - ml[r], 0.f);
        lvv[r][nt] = lv;
        Ps[w][g*4+r][nt*16 + c] = f2bf(__expf(lv));
      }
    }
    __syncthreads();   // P staged (cross-lane redistribution); also fences Ps RAW
    const bf16x8 pf0 = *(const bf16x8*)&Ps[w][c][g*8];
    const bf16x8 pf1 = *(const bf16x8*)&Ps[w][c][g*8 + 32];
    #pragma unroll
    for (int nt=0; nt<4; nt++){
      const bf16x8 vf0 = *(const bf16x8*)&Vs[nt*16 + c][g*8];
      const bf16x8 vf1 = *(const bf16x8*)&Vs[nt*16 + c][g*8 + 32];
      o[nt] = __builtin_amdgcn_mfma_f32_16x16x32_bf16(pf0, vf0, o[nt], 0,0,0);
      o[nt] = __builtin_amdgcn_mfma_f32_16x16x32_bf16(pf1, vf1, o[nt], 0,0,0);
    }
    // la stores issued after PV so the next barrier's vmcnt drain overlaps compute
    #pragma unroll
    for (int r=0;r<4;r++){
      const int qi = q0 + w*16 + g*4 + r;
      float* lrow = la + ((size_t)bh*S_ + qi)*S_ + j0 + c;
      #pragma unroll
      for (int nt=0;nt<4;nt++) lrow[nt*16] = lvv[r][nt];
    }
  }

  // ---- write ctx (bf16, [B,S,D] head-interleaved) ----
  #pragma unroll
  for (int r=0;r<4;r++){
    const int qi = q0 + w*16 + g*4 + r;
    u16* crow = ctx + ((size_t)b*S_ + qi)*D_ + h*DK_ + c;
    #pragma unroll
    for (int nt=0;nt<4;nt++) crow[nt*16] = f2bf(o[nt][r]);
  }
}

extern "C" void kernel_launch(void* const* d_in, const int* in_sizes, int n_in,
                              void* d_out, int out_size, void* d_ws, size_t ws_size,
                              hipStream_t stream)
{
  const float* query = (const float*)d_in[0];
  const float* key   = (const float*)d_in[1];
  const float* value = (const float*)d_in[2];
  const int* mask    = (const int*)d_in[3];
  const float* Wq = (const float*)d_in[4];  const float* bq = (const float*)d_in[5];
  const float* Wk = (const float*)d_in[6];  const float* bk = (const float*)d_in[7];
  const float* Wv = (const float*)d_in[8];  const float* bv = (const float*)d_in[9];
  const float* Wo = (const float*)d_in[10]; const float* bo = (const float*)d_in[11];

  float* out = (float*)d_out;                      // [B,S,D] f32
  float* la  = out + (size_t)B_*S_*D_;             // [B,H,S,S] f32
  u16* qkvws = (u16*)d_ws;                         // Q,K: [BH,S,DK]; V: [BH,DK,S] bf16
  u16* ctx = qkvws + (size_t)3*BH_*S_*DK_;         // [B,S,D] bf16

  dim3 blk(16,16,1);
  proj_qkv<<<dim3(64,12,3), blk, 0, stream>>>(query,key,value,Wq,bq,Wk,bk,Wv,bv,qkvws);
  attn<<<dim3(S_/64, BH_,1), dim3(256,1,1), 0, stream>>>(qkvws, mask, la, ctx);
  proj_o<<<dim3(64,12,1), blk, 0, stream>>>(ctx, Wo, bo, out);
}

// Round 2
// 707.612 us; speedup vs baseline: 3.5195x; 1.1909x over previous
//
#include <hip/hip_runtime.h>

#define B_ 2
#define S_ 2048
#define D_ 768
#define H_ 12
#define DK_ 64
#define BH_ (B_*H_)
#define NEGV (-1e9f)
#define SCALE 0.125f
#define MINIT (-1e30f)

typedef unsigned short u16;
typedef __attribute__((ext_vector_type(8))) short bf16x8;   // 8 bf16 (4 VGPRs)
typedef __attribute__((ext_vector_type(4))) float f32x4;    // MFMA accumulator

__device__ __forceinline__ float bf2f(u16 u){
  union { unsigned int i; float f; } v; v.i = ((unsigned int)u) << 16; return v.f;
}
__device__ __forceinline__ u16 f2bf(float f){
  union { float f; unsigned int i; } v; v.f = f;
  unsigned int x = v.i;
  return (u16)((x + 0x7FFFu + ((x >> 16) & 1u)) >> 16);
}
// split f32 into bf16 hi (truncated) + bf16 lo (truncated residual).
// x = hi + lo + eps, |eps| <= 2^-14 |x|  -> 3-term MFMA gives ~f32 GEMM accuracy.
__device__ __forceinline__ void split2(float x, u16& h, u16& l){
  const unsigned int xi = __float_as_uint(x);
  h = (u16)(xi >> 16);
  const float lo = x - __uint_as_float(xi & 0xFFFF0000u);   // exact (Sterbenz)
  l = (u16)(__float_as_uint(lo) >> 16);
}

// ---------------- MFMA GEMM: C[r,c] = sum_k A[r,k]*B[c,k] (+bias), K=768
// 128x128 tile, 4 waves (2x2), each wave 64x64 out = 4x4 fragments of 16x16x32 bf16 MFMA.
// XBF16: A is bf16 (ctx) -> hi only (2 MFMA/pair); else f32 hi/lo split (3 MFMA/pair).
// OMODE: 0 = f32 plain [M,768] (bias by col)
//        1 = bf16 head-split [bh][s][dk]   (A=X rows=M, B=W rows=N, bias by col)
//        2 = bf16 V-transposed [bh][dk][s] (A=W rows=N, B=X rows=M, bias by A-row)
template<bool XBF16, int OMODE>
__device__ __forceinline__ void gemmM(const void* __restrict__ Xp_, const float* __restrict__ W,
                                      const float* __restrict__ bias, void* __restrict__ outp)
{
  const int bx = blockIdx.x, by = blockIdx.y;
  const int tid  = threadIdx.x;
  const int lane = tid & 63;
  const int w    = tid >> 6;      // wave 0..3
  const int g    = lane >> 4;     // 16-lane group
  const int c    = lane & 15;
  const int wr   = w >> 1, wc = w & 1;

  __shared__ u16 Ah[128][36];
  __shared__ u16 Al[128][36];
  __shared__ u16 Bh[128][36];
  __shared__ u16 Bl[128][36];

  const int ar0 = (OMODE==2 ? by : bx) * 128;   // A row base
  const int br0 = (OMODE==2 ? bx : by) * 128;   // B row base

  const float* __restrict__ Afp = (OMODE==2) ? W : (const float*)Xp_;
  const float* __restrict__ Bfp = (OMODE==2) ? (const float*)Xp_ : W;
  const u16*   __restrict__ Abp = (const u16*)Xp_;

  f32x4 acc[4][4];
  #pragma unroll
  for (int m=0;m<4;m++)
    #pragma unroll
    for (int n=0;n<4;n++) acc[m][n] = (f32x4){0.f,0.f,0.f,0.f};

  for (int k0 = 0; k0 < D_; k0 += 32) {
    __syncthreads();
    if constexpr (XBF16) {
      #pragma unroll
      for (int i=0;i<2;i++){
        const int ci = tid + i*256;            // 0..511
        const int row = ci >> 2, c8 = (ci & 3) * 8;
        *(uint4*)&Ah[row][c8] = *(const uint4*)(Abp + (size_t)(ar0+row)*D_ + k0 + c8);
      }
    } else {
      #pragma unroll
      for (int i=0;i<4;i++){
        const int ci = tid + i*256;            // 0..1023
        const int row = ci >> 3, c4 = (ci & 7) * 4;
        float4 v = *(const float4*)(Afp + (size_t)(ar0+row)*D_ + k0 + c4);
        ushort4 hv, lv;
        split2(v.x,hv.x,lv.x); split2(v.y,hv.y,lv.y); split2(v.z,hv.z,lv.z); split2(v.w,hv.w,lv.w);
        *(ushort4*)&Ah[row][c4] = hv;
        *(ushort4*)&Al[row][c4] = lv;
      }
    }
    #pragma unroll
    for (int i=0;i<4;i++){
      const int ci = tid + i*256;
      const int row = ci >> 3, c4 = (ci & 7) * 4;
      float4 v = *(const float4*)(Bfp + (size_t)(br0+row)*D_ + k0 + c4);
      ushort4 hv, lv;
      split2(v.x,hv.x,lv.x); split2(v.y,hv.y,lv.y); split2(v.z,hv.z,lv.z); split2(v.w,hv.w,lv.w);
      *(ushort4*)&Bh[row][c4] = hv;
      *(ushort4*)&Bl[row][c4] = lv;
    }
    __syncthreads();

    bf16x8 ah[4], al[4], bh[4], bl[4];
    #pragma unroll
    for (int m=0;m<4;m++){
      ah[m] = *(const bf16x8*)&Ah[wr*64 + m*16 + c][g*8];
      if constexpr (!XBF16) al[m] = *(const bf16x8*)&Al[wr*64 + m*16 + c][g*8];
    }
    #pragma unroll
    for (int n=0;n<4;n++){
      bh[n] = *(const bf16x8*)&Bh[wc*64 + n*16 + c][g*8];
      bl[n] = *(const bf16x8*)&Bl[wc*64 + n*16 + c][g*8];
    }
    #pragma unroll
    for (int m=0;m<4;m++)
      #pragma unroll
      for (int n=0;n<4;n++){
        acc[m][n] = __builtin_amdgcn_mfma_f32_16x16x32_bf16(ah[m], bh[n], acc[m][n], 0,0,0);
        acc[m][n] = __builtin_amdgcn_mfma_f32_16x16x32_bf16(ah[m], bl[n], acc[m][n], 0,0,0);
        if constexpr (!XBF16)
          acc[m][n] = __builtin_amdgcn_mfma_f32_16x16x32_bf16(al[m], bh[n], acc[m][n], 0,0,0);
      }
  }

  // ---- epilogue (C layout: col=lane&15, row=(lane>>4)*4+reg) ----
  if constexpr (OMODE==0) {
    float* out = (float*)outp;
    float bb[4];
    #pragma unroll
    for (int n=0;n<4;n++) bb[n] = bias[br0 + wc*64 + n*16 + c];
    #pragma unroll
    for (int m=0;m<4;m++)
      #pragma unroll
      for (int r=0;r<4;r++){
        const int rg = ar0 + wr*64 + m*16 + g*4 + r;
        #pragma unroll
        for (int n=0;n<4;n++)
          out[(size_t)rg*D_ + br0 + wc*64 + n*16 + c] = acc[m][n][r] + bb[n];
      }
  } else if constexpr (OMODE==1) {
    u16* out = (u16*)outp;
    float bb[4];
    #pragma unroll
    for (int n=0;n<4;n++) bb[n] = bias[br0 + wc*64 + n*16 + c];
    #pragma unroll
    for (int m=0;m<4;m++)
      #pragma unroll
      for (int r=0;r<4;r++){
        const int rg = ar0 + wr*64 + m*16 + g*4 + r;
        const int batch = rg >> 11, s = rg & (S_-1);
        #pragma unroll
        for (int n=0;n<4;n++){
          const int col = br0 + wc*64 + n*16 + c;
          const int hh = col >> 6, dk = col & 63;
          out[((size_t)(batch*H_ + hh)*S_ + s)*DK_ + dk] = f2bf(acc[m][n][r] + bb[n]);
        }
      }
  } else {  // OMODE==2: V^T [bh][dk][s]
    u16* out = (u16*)outp;
    #pragma unroll
    for (int m=0;m<4;m++)
      #pragma unroll
      for (int r=0;r<4;r++){
        const int dkg = ar0 + wr*64 + m*16 + g*4 + r;   // over W rows (768)
        const int hh = dkg >> 6, dkl = dkg & 63;
        const float bb = bias[dkg];
        #pragma unroll
        for (int n=0;n<4;n++){
          const int sg = br0 + wc*64 + n*16 + c;        // over X rows (4096)
          const int batch = sg >> 11, s = sg & (S_-1);
          out[((size_t)(batch*H_ + hh)*DK_ + dkl)*S_ + s] = f2bf(acc[m][n][r] + bb);
        }
      }
  }
}

__global__ __launch_bounds__(256) void proj_qkv(
    const float* __restrict__ Xq, const float* __restrict__ Xk, const float* __restrict__ Xv,
    const float* __restrict__ Wq, const float* __restrict__ bq,
    const float* __restrict__ Wk, const float* __restrict__ bk,
    const float* __restrict__ Wv, const float* __restrict__ bv,
    u16* __restrict__ qkv)
{
  const int z = blockIdx.z;
  u16* out = qkv + (size_t)z * ((size_t)BH_*S_*DK_);
  if (z==0)      gemmM<false,1>((const void*)Xq, Wq, bq, (void*)out);
  else if (z==1) gemmM<false,1>((const void*)Xk, Wk, bk, (void*)out);
  else           gemmM<false,2>((const void*)Xv, Wv, bv, (void*)out);
}

__global__ __launch_bounds__(256) void proj_o(
    const u16* __restrict__ Xc, const float* __restrict__ Wo, const float* __restrict__ bo,
    float* __restrict__ out)
{
  gemmM<true,0>((const void*)Xc, Wo, bo, (void*)out);
}

// ---------------- attention (MFMA) ----------------
// Stage a 64x64 bf16 tile (row-major source, stride sstride) into LDS [64][72].
__device__ __forceinline__ void stage64(u16 (*dst)[72], const u16* __restrict__ src,
                                        size_t sstride, int tid)
{
  #pragma unroll
  for (int i=0;i<2;i++){
    const int cidx = tid + i*256;         // 0..511
    const int row = cidx >> 3, cc = (cidx & 7) << 3;
    uint4 v = *(const uint4*)(src + (size_t)row*sstride + cc);
    *(uint4*)&dst[row][cc] = v;
  }
}

__global__ __launch_bounds__(256,3) void attn(const u16* __restrict__ qkv, const int* __restrict__ mask,
                                              float* __restrict__ la, u16* __restrict__ ctx)
{
  const int bh = blockIdx.y;
  const int q0 = blockIdx.x * 64;
  const int b = bh / H_;
  const int h = bh - b*H_;
  const u16* Qp = qkv + (size_t)bh * S_ * DK_;             // [S][DK]
  const u16* Kp = qkv + (size_t)(BH_ + bh) * S_ * DK_;     // [S][DK]
  const u16* Vt = qkv + (size_t)(2*BH_ + bh) * S_ * DK_;   // [DK][S]  (transposed by proj)
  const int* Mp = mask + (size_t)b * S_ * S_;

  const int tid  = threadIdx.x;
  const int w    = tid >> 6;      // wave 0..3
  const int lane = tid & 63;
  const int g    = lane >> 4;     // 16-lane group 0..3
  const int c    = lane & 15;

  __shared__ u16 Ks[64][72];
  __shared__ u16 Vs[64][72];      // Vs[d][k] = V[j0+k][d]
  __shared__ u16 Ps[4][16][72];   // per-wave P strip (C-layout write -> A-frag read)

  stage64(Ks, Qp + (size_t)q0*DK_, DK_, tid);
  __syncthreads();
  const bf16x8 qf0 = *(const bf16x8*)&Ks[w*16 + c][g*8];
  const bf16x8 qf1 = *(const bf16x8*)&Ks[w*16 + c][g*8 + 32];

  float mt[4], lt[4];
  #pragma unroll
  for (int r=0;r<4;r++){ mt[r] = MINIT; lt[r] = 0.f; }

  // ---- pass A: per-lane online stats ----
  for (int j0=0; j0<S_; j0+=64){
    __syncthreads();
    stage64(Ks, Kp + (size_t)j0*DK_, DK_, tid);
    __syncthreads();
    f32x4 sc[4];
    #pragma unroll
    for (int nt=0; nt<4; nt++){
      const bf16x8 kf0 = *(const bf16x8*)&Ks[nt*16 + c][g*8];
      const bf16x8 kf1 = *(const bf16x8*)&Ks[nt*16 + c][g*8 + 32];
      f32x4 z = {0.f,0.f,0.f,0.f};
      z      = __builtin_amdgcn_mfma_f32_16x16x32_bf16(qf0, kf0, z, 0,0,0);
      sc[nt] = __builtin_amdgcn_mfma_f32_16x16x32_bf16(qf1, kf1, z, 0,0,0);
    }
    #pragma unroll
    for (int r=0;r<4;r++){
      const int qi = q0 + w*16 + g*4 + r;
      const int* mp = Mp + (size_t)qi*S_ + j0 + c;
      float sv[4];
      #pragma unroll
      for (int nt=0;nt<4;nt++)
        sv[nt] = mp[nt*16] ? sc[nt][r]*SCALE : NEGV;
      const float cm = fmaxf(fmaxf(sv[0],sv[1]), fmaxf(sv[2],sv[3]));
      const float mn = fmaxf(mt[r], cm);
      lt[r] = lt[r]*__expf(mt[r]-mn)
            + __expf(sv[0]-mn) + __expf(sv[1]-mn) + __expf(sv[2]-mn) + __expf(sv[3]-mn);
      mt[r] = mn;
    }
  }

  // ---- merge (m,l) across the 16 lanes of each group ----
  float ml[4];
  #pragma unroll
  for (int r=0;r<4;r++){
    float m = mt[r], l = lt[r];
    #pragma unroll
    for (int st=1; st<16; st<<=1){
      const float m2 = __shfl_xor(m, st);
      const float l2 = __shfl_xor(l, st);
      const float mn = fmaxf(m, m2);
      l = l*__expf(m-mn) + l2*__expf(m2-mn);
      m = mn;
    }
    ml[r] = m + __logf(fmaxf(l, 1e-30f));
  }

  // ---- pass B: recompute scores, emit log_attn, MFMA P.V ----
  f32x4 o[4];
  #pragma unroll
  for (int nt=0;nt<4;nt++) o[nt] = (f32x4){0.f,0.f,0.f,0.f};

  for (int j0=0; j0<S_; j0+=64){
    __syncthreads();
    stage64(Ks, Kp + (size_t)j0*DK_, DK_, tid);
    stage64(Vs, Vt + j0, S_, tid);
    __syncthreads();
    f32x4 sc[4];
    #pragma unroll
    for (int nt=0; nt<4; nt++){
      const bf16x8 kf0 = *(const bf16x8*)&Ks[nt*16 + c][g*8];
      const bf16x8 kf1 = *(const bf16x8*)&Ks[nt*16 + c][g*8 + 32];
      f32x4 z = {0.f,0.f,0.f,0.f};
      z      = __builtin_amdgcn_mfma_f32_16x16x32_bf16(qf0, kf0, z, 0,0,0);
      sc[nt] = __builtin_amdgcn_mfma_f32_16x16x32_bf16(qf1, kf1, z, 0,0,0);
    }
    float lvv[4][4];
    #pragma unroll
    for (int r=0;r<4;r++){
      const int qi = q0 + w*16 + g*4 + r;
      const int* mp = Mp + (size_t)qi*S_ + j0 + c;
      #pragma unroll
      for (int nt=0;nt<4;nt++){
        const float s  = mp[nt*16] ? sc[nt][r]*SCALE : NEGV;
        const float lv = fminf(s - ml[r], 0.f);
        lvv[r][nt] = lv;
        Ps[w][g*4+r][nt*16 + c] = f2bf(__expf(lv));
      }
    }
    __syncthreads();   // P staged; also fences Ks/Vs RAW for next iter
    const bf16x8 pf0 = *(const bf16x8*)&Ps[w][c][g*8];
    const bf16x8 pf1 = *(const bf16x8*)&Ps[w][c][g*8 + 32];
    #pragma unroll
    for (int nt=0; nt<4; nt++){
      const bf16x8 vf0 = *(const bf16x8*)&Vs[nt*16 + c][g*8];
      const bf16x8 vf1 = *(const bf16x8*)&Vs[nt*16 + c][g*8 + 32];
      o[nt] = __builtin_amdgcn_mfma_f32_16x16x32_bf16(pf0, vf0, o[nt], 0,0,0);
      o[nt] = __builtin_amdgcn_mfma_f32_16x16x32_bf16(pf1, vf1, o[nt], 0,0,0);
    }
    #pragma unroll
    for (int r=0;r<4;r++){
      const int qi = q0 + w*16 + g*4 + r;
      float* lrow = la + ((size_t)bh*S_ + qi)*S_ + j0 + c;
      #pragma unroll
      for (int nt=0;nt<4;nt++) lrow[nt*16] = lvv[r][nt];
    }
  }

  #pragma unroll
  for (int r=0;r<4;r++){
    const int qi = q0 + w*16 + g*4 + r;
    u16* crow = ctx + ((size_t)b*S_ + qi)*D_ + h*DK_ + c;
    #pragma unroll
    for (int nt=0;nt<4;nt++) crow[nt*16] = f2bf(o[nt][r]);
  }
}

extern "C" void kernel_launch(void* const* d_in, const int* in_sizes, int n_in,
                              void* d_out, int out_size, void* d_ws, size_t ws_size,
                              hipStream_t stream)
{
  const float* query = (const float*)d_in[0];
  const float* key   = (const float*)d_in[1];
  const float* value = (const float*)d_in[2];
  const int* mask    = (const int*)d_in[3];
  const float* Wq = (const float*)d_in[4];  const float* bq = (const float*)d_in[5];
  const float* Wk = (const float*)d_in[6];  const float* bk = (const float*)d_in[7];
  const float* Wv = (const float*)d_in[8];  const float* bv = (const float*)d_in[9];
  const float* Wo = (const float*)d_in[10]; const float* bo = (const float*)d_in[11];

  float* out = (float*)d_out;                      // [B,S,D] f32
  float* la  = out + (size_t)B_*S_*D_;             // [B,H,S,S] f32
  u16* qkvws = (u16*)d_ws;                         // Q,K: [BH,S,DK]; V: [BH,DK,S] bf16
  u16* ctx = qkvws + (size_t)3*BH_*S_*DK_;         // [B,S,D] bf16

  proj_qkv<<<dim3(32,6,3), dim3(256,1,1), 0, stream>>>(query,key,value,Wq,bq,Wk,bk,Wv,bv,qkvws);
  attn<<<dim3(S_/64, BH_,1), dim3(256,1,1), 0, stream>>>(qkvws, mask, la, ctx);
  proj_o<<<dim3(32,6,1), dim3(256,1,1), 0, stream>>>(ctx, Wo, bo, out);
}